// Round 1
// baseline (92.758 us; speedup 1.0000x reference)
//
#include <hip/hip_runtime.h>
#include <hip/hip_bf16.h>

#define N_F 100
#define N_B 4096
#define DH 96
#define DT 192
#define BM 64
#define HPAD 100   // bf16 elems per LDS row (pad from 96; 200B stride, 8B-aligned)

typedef unsigned short u16;
typedef unsigned int u32;
typedef __bf16 bf16x8 __attribute__((ext_vector_type(8)));
typedef float f32x4 __attribute__((ext_vector_type(4)));

union FragAB { bf16x8 v; uint2 q2[2]; };

static __device__ __forceinline__ u16 f2bf(float v) {
    u32 b = __float_as_uint(v);
    return (u16)((b + 0x7FFFu + ((b >> 16) & 1u)) >> 16);  // RNE, no NaN in data
}

// Pre-convert + transpose W2[f][k][n] (f32) -> W2T[f][n][k] (bf16) in d_ws.
__global__ void convert_w2_kernel(const float* __restrict__ W2, u16* __restrict__ W2T) {
    int idx = blockIdx.x * 256 + threadIdx.x;   // f,n,k with k fastest -> coalesced writes
    if (idx >= N_F * DT * DH) return;
    int f = idx / (DT * DH);
    int r = idx - f * DT * DH;
    int n = r / DH;
    int k = r - n * DH;
    W2T[idx] = f2bf(W2[(f * DH + k) * DT + n]);
}

template <bool USE_WS>
__global__ __launch_bounds__(256) void mlp_tok_kernel(
    const float* __restrict__ x, const float* __restrict__ W1,
    const float* __restrict__ b1, const float* __restrict__ W2,
    const float* __restrict__ b2, const u16* __restrict__ W2T,
    float* __restrict__ out)
{
    const int f   = blockIdx.y;
    const int b0  = blockIdx.x * BM;
    const int tid = threadIdx.x;
    const int lane = tid & 63;
    const int wv   = tid >> 6;           // wave id 0..3 -> 48-col strip

    __shared__ float x_lds[BM];
    __shared__ u16 h_lds[BM][HPAD];
    __shared__ u16 w2t_lds[USE_WS ? 1 : DT][HPAD];

    if (tid < BM) x_lds[tid] = x[(size_t)(b0 + tid) * N_F + f];
    __syncthreads();

    // ---- Phase 1: h = gelu_exact(x*W1 + b1) -> bf16 LDS [row][k] ----
    {
        const int row = tid & (BM - 1);
        const int kc  = (tid >> 6) * 24;           // 4 chunks of 24 k each
        const float xv = x_lds[row];
        #pragma unroll
        for (int c = 0; c < 6; ++c) {
            const int k = kc + c * 4;
            const float4 w1v = *(const float4*)&W1[f * DH + k];
            const float4 b1v = *(const float4*)&b1[f * DH + k];
            float p0 = fmaf(xv, w1v.x, b1v.x);
            float p1 = fmaf(xv, w1v.y, b1v.y);
            float p2 = fmaf(xv, w1v.z, b1v.z);
            float p3 = fmaf(xv, w1v.w, b1v.w);
            const float c0 = 0.70710678118654752f;
            float g0 = 0.5f * p0 * (1.0f + erff(p0 * c0));
            float g1 = 0.5f * p1 * (1.0f + erff(p1 * c0));
            float g2 = 0.5f * p2 * (1.0f + erff(p2 * c0));
            float g3 = 0.5f * p3 * (1.0f + erff(p3 * c0));
            uint2 pk;
            pk.x = (u32)f2bf(g0) | ((u32)f2bf(g1) << 16);
            pk.y = (u32)f2bf(g2) | ((u32)f2bf(g3) << 16);
            *(uint2*)&h_lds[row][k] = pk;
        }
    }

    // ---- Fallback: stage W2[f] transposed into LDS as bf16 [n][k] ----
    if constexpr (!USE_WS) {
        #pragma unroll
        for (int i = 0; i < (DT * DH) / (256 * 4); ++i) {   // 18 iters
            const int e = (i * 256 + tid) * 4;
            const int k = e / DT;                 // 192 % 4 == 0 -> same k for 4 n
            const int n = e - k * DT;
            const float4 wv4 = *(const float4*)&W2[(f * DH + k) * DT + n];
            w2t_lds[n + 0][k] = f2bf(wv4.x);
            w2t_lds[n + 1][k] = f2bf(wv4.y);
            w2t_lds[n + 2][k] = f2bf(wv4.z);
            w2t_lds[n + 3][k] = f2bf(wv4.w);
        }
    }
    __syncthreads();

    // ---- Phase 2: MFMA. Wave wv: cols [wv*48, wv*48+48), all 64 rows ----
    const int q    = lane >> 4;          // quarter-wave -> k sub-offset
    const int mrow = lane & 15;

    f32x4 acc[4][3];
    #pragma unroll
    for (int mt = 0; mt < 4; ++mt)
        #pragma unroll
        for (int nt = 0; nt < 3; ++nt)
            acc[mt][nt] = (f32x4){0.f, 0.f, 0.f, 0.f};

    const u16* __restrict__ w2tf = USE_WS ? (W2T + (size_t)f * DT * DH) : nullptr;

    #pragma unroll
    for (int ks = 0; ks < 3; ++ks) {
        const int k0 = ks * 32 + q * 4;
        FragAB a[4], bf[3];
        #pragma unroll
        for (int mt = 0; mt < 4; ++mt) {
            a[mt].q2[0] = *(const uint2*)&h_lds[mt * 16 + mrow][k0];
            a[mt].q2[1] = *(const uint2*)&h_lds[mt * 16 + mrow][k0 + 16];
        }
        #pragma unroll
        for (int nt = 0; nt < 3; ++nt) {
            const int n = wv * 48 + nt * 16 + mrow;
            if constexpr (USE_WS) {
                bf[nt].q2[0] = *(const uint2*)&w2tf[n * DH + k0];
                bf[nt].q2[1] = *(const uint2*)&w2tf[n * DH + k0 + 16];
            } else {
                bf[nt].q2[0] = *(const uint2*)&w2t_lds[n][k0];
                bf[nt].q2[1] = *(const uint2*)&w2t_lds[n][k0 + 16];
            }
        }
        #pragma unroll
        for (int mt = 0; mt < 4; ++mt)
            #pragma unroll
            for (int nt = 0; nt < 3; ++nt)
                acc[mt][nt] = __builtin_amdgcn_mfma_f32_16x16x32_bf16(
                    a[mt].v, bf[nt].v, acc[mt][nt], 0, 0, 0);
    }

    // ---- Epilogue: +b2, store f32. C/D: col=lane&15, row=4*(lane>>4)+reg ----
    float b2v[3];
    #pragma unroll
    for (int nt = 0; nt < 3; ++nt)
        b2v[nt] = b2[f * DT + wv * 48 + nt * 16 + mrow];

    #pragma unroll
    for (int mt = 0; mt < 4; ++mt) {
        #pragma unroll
        for (int nt = 0; nt < 3; ++nt) {
            const int d = wv * 48 + nt * 16 + mrow;
            #pragma unroll
            for (int j = 0; j < 4; ++j) {
                const int b = b0 + mt * 16 + q * 4 + j;
                out[((size_t)b * N_F + f) * DT + d] = acc[mt][nt][j] + b2v[nt];
            }
        }
    }
}

extern "C" void kernel_launch(void* const* d_in, const int* in_sizes, int n_in,
                              void* d_out, int out_size, void* d_ws, size_t ws_size,
                              hipStream_t stream) {
    const float* x  = (const float*)d_in[0];
    const float* W1 = (const float*)d_in[1];
    const float* b1 = (const float*)d_in[2];
    const float* W2 = (const float*)d_in[3];
    const float* b2 = (const float*)d_in[4];
    float* out = (float*)d_out;

    const size_t w2t_bytes = (size_t)N_F * DT * DH * sizeof(u16);
    dim3 grid(N_B / BM, N_F);

    if (ws_size >= w2t_bytes) {
        u16* W2T = (u16*)d_ws;
        convert_w2_kernel<<<(N_F * DT * DH + 255) / 256, 256, 0, stream>>>(W2, W2T);
        mlp_tok_kernel<true><<<grid, 256, 0, stream>>>(x, W1, b1, W2, b2, W2T, out);
    } else {
        mlp_tok_kernel<false><<<grid, 256, 0, stream>>>(x, W1, b1, W2, b2, nullptr, out);
    }
}